// Round 4
// baseline (146.866 us; speedup 1.0000x reference)
//
#include <hip/hip_runtime.h>

// Chamfer distance, B=8, N=M=8192, D=3, fp32.
// e(pair) = fma(x,-2cx, fma(y,-2cy, fma(z,-2cz, ||c||^2))) for 2 candidates
// at once via one inline-asm block of 3 chained v_pk_fma_f32 (full-rate
// packed fp32). Both halves fold into the running per-point min with a
// single v_min3_f32 (ISel-matched from fminf(fminf(..))).
// => 2.0 VALU issues/pair core, ~2.3 incl. LDS reads + loop overhead.

typedef float f2 __attribute__((ext_vector_type(2)));

constexpr int B     = 8;
constexpr int NPTS  = 8192;
constexpr int TOTAL = B * NPTS;      // 65536
constexpr int TN    = 2048;          // A-points per block (256 thr * P)
constexpr int TM    = 512;           // candidates per block chunk
constexpr int NCH   = NPTS / TM;     // 16 candidate chunks
constexpr int P     = 8;             // A-points per thread

// grid (NPTS/TN=4, NCH=16, 16).  z = dir*8 + b.
// Writes per-chunk partial-min planes: dist[(z*NCH+chunk)*NPTS + n].
// max(d,0) clamp commutes with the cross-chunk min (monotone).
__global__ __launch_bounds__(256, 4) void chamfer_min(
    const float* __restrict__ in1, const float* __restrict__ in2,
    float* __restrict__ dist)
{
    const int z   = blockIdx.z;
    const int dir = z >> 3;
    const int b   = z & 7;

    const float* Araw = (dir ? in2 : in1) + (size_t)b * NPTS * 3;
    const float* Craw = (dir ? in1 : in2) + (size_t)b * NPTS * 3;
    float* out = dist + ((size_t)z * NCH + blockIdx.y) * NPTS;

    // Candidate chunk in LDS, pair-SoA as f2 quads:
    // lds2[4k+0]=(-2x0,-2x1) lds2[4k+1]=(-2y0,-2y1)
    // lds2[4k+2]=(-2z0,-2z1) lds2[4k+3]=(sq0,sq1)
    __shared__ f2 lds2[TM * 2];
    {
        const int k = threadIdx.x;                 // pair index, 256 pairs
        const float* c = Craw + (size_t)(blockIdx.y * TM + 2 * k) * 3;
        float x0 = c[0], y0 = c[1], z0 = c[2];
        float x1 = c[3], y1 = c[4], z1 = c[5];
        lds2[4 * k + 0] = f2{-2.f * x0, -2.f * x1};
        lds2[4 * k + 1] = f2{-2.f * y0, -2.f * y1};
        lds2[4 * k + 2] = f2{-2.f * z0, -2.f * z1};
        lds2[4 * k + 3] = f2{fmaf(x0, x0, fmaf(y0, y0, z0 * z0)),
                             fmaf(x1, x1, fmaf(y1, y1, z1 * z1))};
    }

    // A-points: persistent splat pairs {x,x},{y,y},{z,z}; scalar sq, min.
    const int nbase = blockIdx.x * TN + threadIdx.x;
    f2 X[P], Y[P], Z[P];
    float SQ[P], MN[P];
#pragma unroll
    for (int p = 0; p < P; ++p) {
        const float* a = Araw + (size_t)(nbase + p * 256) * 3;
        float ax = a[0], ay = a[1], az = a[2];
        X[p] = f2{ax, ax};
        Y[p] = f2{ay, ay};
        Z[p] = f2{az, az};
        SQ[p] = fmaf(ax, ax, fmaf(ay, ay, az * az));
        MN[p] = 1e30f;
    }
    __syncthreads();

#pragma unroll 4
    for (int k = 0; k < TM / 2; ++k) {
        f2 cx = lds2[4 * k + 0];       // wave-uniform addr: LDS broadcast
        f2 cy = lds2[4 * k + 1];
        f2 cz = lds2[4 * k + 2];
        f2 cw = lds2[4 * k + 3];
#pragma unroll
        for (int p = 0; p < P; ++p) {
            f2 e;
            asm("v_pk_fma_f32 %0, %1, %2, %3\n\t"
                "v_pk_fma_f32 %0, %4, %5, %0\n\t"
                "v_pk_fma_f32 %0, %6, %7, %0"
                : "=&v"(e)
                : "v"(Z[p]), "v"(cz), "v"(cw),
                  "v"(Y[p]), "v"(cy),
                  "v"(X[p]), "v"(cx));
            // v_min3_f32 via ISel pattern: one issue merges both halves.
            MN[p] = fminf(fminf(MN[p], e.x), e.y);
        }
    }

#pragma unroll
    for (int p = 0; p < P; ++p)
        out[nbase + p * 256] = fmaxf(MN[p] + SQ[p], 0.0f);
}

// One thread per (z,n): min across the NCH chunk planes, block-sum,
// atomicAdd(out, sum/TOTAL). loss = (sum of all 2*TOTAL mins)/TOTAL.
__global__ __launch_bounds__(256) void reduce_kernel(
    const float* __restrict__ dist, float* __restrict__ out)
{
    int g = blockIdx.x * 256 + threadIdx.x;     // [0, 2*TOTAL)
    int z = g >> 13;
    int n = g & (NPTS - 1);
    const float* base = dist + (size_t)z * NCH * NPTS + n;
    float v = base[0];
#pragma unroll
    for (int cy = 1; cy < NCH; ++cy)
        v = fminf(v, base[(size_t)cy * NPTS]);

#pragma unroll
    for (int off = 32; off; off >>= 1)
        v += __shfl_down(v, off, 64);
    __shared__ float wsum[4];
    int lane = threadIdx.x & 63, w = threadIdx.x >> 6;
    if (lane == 0) wsum[w] = v;
    __syncthreads();
    if (threadIdx.x == 0)
        atomicAdd(out, (wsum[0] + wsum[1] + wsum[2] + wsum[3]) *
                           (1.0f / (float)TOTAL));
}

extern "C" void kernel_launch(void* const* d_in, const int* in_sizes, int n_in,
                              void* d_out, int out_size, void* d_ws, size_t ws_size,
                              hipStream_t stream)
{
    const float* in1 = (const float*)d_in[0];
    const float* in2 = (const float*)d_in[1];
    float* out = (float*)d_out;

    float* dist = (float*)d_ws;   // 16 z * 16 chunks * 8192 * 4B = 8 MiB

    hipMemsetAsync(out, 0, sizeof(float), stream);   // atomicAdd accumulator

    chamfer_min<<<dim3(NPTS / TN, NCH, 2 * B), 256, 0, stream>>>(in1, in2, dist);
    reduce_kernel<<<(2 * TOTAL) / 256, 256, 0, stream>>>(dist, out);
}

// Round 5
// 99.844 us; speedup vs baseline: 1.4710x; 1.4710x over previous
//
#include <hip/hip_runtime.h>

// Chamfer distance, B=8, N=M=8192, D=3, fp32 — MFMA formulation.
// Each fp32 split into f16 hi+lo (x = xh+xl, err ~2^-22). K=16 vectors:
//   A(n): [ah0,ah1,ah2, al0,al1,al2, ah0,ah1,ah2, sqh_n,sql_n, 1,1, 0,0,0]
//   B(m): [bh0,bh1,bh2, bh0,bh1,bh2, bl0,bl1,bl2, 1,1, sqh_m,sql_m, 0,0,0]
// with b = -2c (exact scale). One v_mfma_f32_32x32x16_f16 then yields a
// 32x32 tile of d(n,m) = sq_n + sq_m - 2<a,c> (+O(1e-5)). Each tile feeds
// BOTH mins: over cols (dist1) and over rows (dist2) — halves pair count.
// Layouts: C/D col=lane&31,row=(reg&3)+8*(reg>>2)+4*(lane>>5) [HW-verified];
// A,B: row/col=lane&31, k=(lane>>5)*8+j [AMD matrix tables].

typedef _Float16 half8  __attribute__((ext_vector_type(8)));
typedef float    f16x   __attribute__((ext_vector_type(16)));

constexpr int B     = 8;
constexpr int NPTS  = 8192;
constexpr int TOTAL = B * NPTS;       // 65536
constexpr int NSTRIP = 256;           // n-rows per block (8 waves * 32)
constexpr int MHALF  = 4096;          // m-range per block
constexpr int CHUNK  = 512;           // m staged in LDS per chunk

// Pack inputs into K=16 f16 vectors (32 B/point). A-side from input1,
// B-side from input2 (pre-scaled by -2).
__global__ __launch_bounds__(256) void pack_kernel(
    const float* __restrict__ in1, const float* __restrict__ in2,
    _Float16* __restrict__ Ap, _Float16* __restrict__ Bp)
{
    int i = blockIdx.x * 256 + threadIdx.x;
    {
        float x = in1[3*i], y = in1[3*i+1], z = in1[3*i+2];
        float sq = fmaf(x, x, fmaf(y, y, z * z));
        _Float16 xh = (_Float16)x, yh = (_Float16)y, zh = (_Float16)z;
        _Float16 xl = (_Float16)(x - (float)xh);
        _Float16 yl = (_Float16)(y - (float)yh);
        _Float16 zl = (_Float16)(z - (float)zh);
        _Float16 sh = (_Float16)sq, sl = (_Float16)(sq - (float)sh);
        half8 lo = {xh, yh, zh, xl, yl, zl, xh, yh};
        half8 hi = {zh, sh, sl, (_Float16)1.f, (_Float16)1.f,
                    (_Float16)0.f, (_Float16)0.f, (_Float16)0.f};
        *(half8*)&Ap[16 * i] = lo;
        *(half8*)&Ap[16 * i + 8] = hi;
    }
    {
        float x = -2.f * in2[3*i], y = -2.f * in2[3*i+1], z = -2.f * in2[3*i+2];
        float cx = in2[3*i], cy = in2[3*i+1], cz = in2[3*i+2];
        float sq = fmaf(cx, cx, fmaf(cy, cy, cz * cz));
        _Float16 xh = (_Float16)x, yh = (_Float16)y, zh = (_Float16)z;
        _Float16 xl = (_Float16)(x - (float)xh);
        _Float16 yl = (_Float16)(y - (float)yh);
        _Float16 zl = (_Float16)(z - (float)zh);
        _Float16 sh = (_Float16)sq, sl = (_Float16)(sq - (float)sh);
        half8 lo = {xh, yh, zh, xh, yh, zh, xl, yl};
        half8 hi = {zl, (_Float16)1.f, (_Float16)1.f, sh, sl,
                    (_Float16)0.f, (_Float16)0.f, (_Float16)0.f};
        *(half8*)&Bp[16 * i] = lo;
        *(half8*)&Bp[16 * i + 8] = hi;
    }
}

// grid (NPTS/NSTRIP=32, 2, 8), block 512 (8 waves, 32 n-rows each).
// Each block: n-strip of 256 rows x m-half of 4096, staged in 512-pt chunks.
// dist1 (min over m) folded in regs per wave -> d1p[b][mhalf][n].
// dist2 (min over n) folded via LDS atomicMin -> d2p[b][strip][m].
__global__ __launch_bounds__(512, 4) void chamfer_mfma(
    const _Float16* __restrict__ Ap, const _Float16* __restrict__ Bp,
    float* __restrict__ d1p, float* __restrict__ d2p)
{
    const int b     = blockIdx.z;
    const int strip = blockIdx.x;
    const int mh    = blockIdx.y;
    const int wave  = threadIdx.x >> 6;
    const int lane  = threadIdx.x & 63;
    const int col   = lane & 31;
    const int half  = lane >> 5;

    __shared__ _Float16 ldsB[CHUNK * 16];      // 16 KiB
    __shared__ unsigned d2lds[MHALF];          // 16 KiB

    for (int i = threadIdx.x; i < MHALF; i += 512)
        d2lds[i] = 0xFFFFFFFFu;

    // Persistent A fragment: row = nbase+col, k-slots half*8..half*8+7.
    const int nbase = strip * NSTRIP + wave * 32;
    half8 afrag = *(const half8*)&Ap[((size_t)b * NPTS + nbase + col) * 16 + half * 8];

    f16x MN1;
#pragma unroll
    for (int r = 0; r < 16; ++r) MN1[r] = 1e30f;
    f16x zero;
#pragma unroll
    for (int r = 0; r < 16; ++r) zero[r] = 0.0f;

    const _Float16* BpB = Bp + ((size_t)b * NPTS + mh * MHALF) * 16;

    for (int c = 0; c < MHALF / CHUNK; ++c) {
        __syncthreads();                       // protect ldsB reuse
        const float4* src = (const float4*)(BpB + (size_t)c * CHUNK * 16);
        float4* dst = (float4*)ldsB;
        dst[threadIdx.x]       = src[threadIdx.x];
        dst[threadIdx.x + 512] = src[threadIdx.x + 512];
        __syncthreads();

#pragma unroll 2
        for (int t = 0; t < CHUNK / 32; t += 2) {
            half8 bfA = *(const half8*)&ldsB[((t    ) * 32 + col) * 16 + half * 8];
            half8 bfB = *(const half8*)&ldsB[((t + 1) * 32 + col) * 16 + half * 8];
            f16x accA = __builtin_amdgcn_mfma_f32_32x32x16_f16(afrag, bfA, zero, 0, 0, 0);
            f16x accB = __builtin_amdgcn_mfma_f32_32x32x16_f16(afrag, bfB, zero, 0, 0, 0);

            // dist1 fold (min over m): per-reg running min, min3-shaped.
#pragma unroll
            for (int r = 0; r < 16; ++r)
                MN1[r] = fminf(fminf(MN1[r], accA[r]), accB[r]);

            // dist2 fold (min over this wave's 32 n-rows), per tile.
            float vA = fminf(fminf(accA[0], accA[1]), accA[2]);
#pragma unroll
            for (int r = 3; r < 16; ++r) vA = fminf(vA, accA[r]);
            vA = fmaxf(vA, 0.0f);
            atomicMin(&d2lds[c * CHUNK + t * 32 + col], __float_as_uint(vA));

            float vB = fminf(fminf(accB[0], accB[1]), accB[2]);
#pragma unroll
            for (int r = 3; r < 16; ++r) vB = fminf(vB, accB[r]);
            vB = fmaxf(vB, 0.0f);
            atomicMin(&d2lds[c * CHUNK + (t + 1) * 32 + col], __float_as_uint(vB));
        }
    }
    __syncthreads();

    // dist2 plane out (clamped already).
    float* d2 = d2p + ((size_t)b * 32 + strip) * NPTS + mh * MHALF;
    for (int i = threadIdx.x; i < MHALF; i += 512)
        d2[i] = __uint_as_float(d2lds[i]);

    // dist1: butterfly min across the 32 lanes of each half (cols), then
    // lane 0 of each half writes its 16 rows. row=(r&3)+8*(r>>2)+4*half.
#pragma unroll
    for (int m = 1; m <= 16; m <<= 1)
#pragma unroll
        for (int r = 0; r < 16; ++r)
            MN1[r] = fminf(MN1[r], __shfl_xor(MN1[r], m, 64));
    if (col == 0) {
        float* d1 = d1p + ((size_t)b * 2 + mh) * NPTS + nbase;
#pragma unroll
        for (int r = 0; r < 16; ++r)
            d1[(r & 3) + 8 * (r >> 2) + 4 * half] = MN1[r];
    }
}

// One thread per (b,m): min over 32 strip planes (dist2) + the same
// thread folds dist1[b][n=m] over its 2 m-half planes. Sum, wave-reduce,
// atomicAdd(out, sum/TOTAL).
__global__ __launch_bounds__(256) void reduce_kernel(
    const float* __restrict__ d1p, const float* __restrict__ d2p,
    float* __restrict__ out)
{
    int g = blockIdx.x * 256 + threadIdx.x;   // [0, TOTAL)
    int b = g >> 13, m = g & (NPTS - 1);
    const float* p2 = d2p + (size_t)b * 32 * NPTS + m;
    float v2 = p2[0];
#pragma unroll
    for (int s = 1; s < 32; ++s)
        v2 = fminf(v2, p2[(size_t)s * NPTS]);
    float v1 = fmaxf(fminf(d1p[((size_t)b * 2 + 0) * NPTS + m],
                           d1p[((size_t)b * 2 + 1) * NPTS + m]), 0.0f);
    float v = v1 + v2;

#pragma unroll
    for (int off = 32; off; off >>= 1)
        v += __shfl_down(v, off, 64);
    __shared__ float wsum[4];
    int lane = threadIdx.x & 63, w = threadIdx.x >> 6;
    if (lane == 0) wsum[w] = v;
    __syncthreads();
    if (threadIdx.x == 0)
        atomicAdd(out, (wsum[0] + wsum[1] + wsum[2] + wsum[3]) *
                           (1.0f / (float)TOTAL));
}

extern "C" void kernel_launch(void* const* d_in, const int* in_sizes, int n_in,
                              void* d_out, int out_size, void* d_ws, size_t ws_size,
                              hipStream_t stream)
{
    const float* in1 = (const float*)d_in[0];
    const float* in2 = (const float*)d_in[1];
    float* out = (float*)d_out;

    char* ws = (char*)d_ws;
    _Float16* Ap  = (_Float16*)ws;                            // 2 MiB
    _Float16* Bp  = (_Float16*)(ws + (size_t)TOTAL * 32);     // 2 MiB
    float*    d1p = (float*)(ws + (size_t)2 * TOTAL * 32);    // 512 KiB
    float*    d2p = (float*)(ws + (size_t)2 * TOTAL * 32 + (size_t)2 * TOTAL * 4); // 8 MiB

    hipMemsetAsync(out, 0, sizeof(float), stream);

    pack_kernel<<<TOTAL / 256, 256, 0, stream>>>(in1, in2, Ap, Bp);
    chamfer_mfma<<<dim3(NPTS / NSTRIP, 2, B), 512, 0, stream>>>(Ap, Bp, d1p, d2p);
    reduce_kernel<<<TOTAL / 256, 256, 0, stream>>>(d1p, d2p, out);
}

// Round 6
// 95.866 us; speedup vs baseline: 1.5320x; 1.0415x over previous
//
#include <hip/hip_runtime.h>

// Chamfer distance, B=8, N=M=8192, D=3, fp32 — MFMA formulation.
// Each fp32 split into f16 hi+lo (x = xh+xl, err ~2^-22). K=16 vectors:
//   A(n): [ah0,ah1,ah2, al0,al1,al2, ah0,ah1,ah2, sqh_n,sql_n, 1,1, 0,0,0]
//   B(m): [bh0,bh1,bh2, bh0,bh1,bh2, bl0,bl1,bl2, 1,1, sqh_m,sql_m, 0,0,0]
// with b = -2c (exact scale). One v_mfma_f32_32x32x16_f16 yields a 32x32
// tile of d(n,m) = sq_n + sq_m - 2<a,c> (+O(1e-5)). Each tile feeds BOTH
// mins: over m (dist1, reg fold) and over n (dist2, LDS atomicMin).
// C/D: col=lane&31, row=(reg&3)+8*(reg>>2)+4*(lane>>5)  [HW-verified]
// A/B: row/col=lane&31, k=(lane>>5)*8+j                 [verified R5: absmax 0]

typedef _Float16 half8 __attribute__((ext_vector_type(8)));
typedef float    f16x  __attribute__((ext_vector_type(16)));

constexpr int B      = 8;
constexpr int NPTS   = 8192;
constexpr int TOTAL  = B * NPTS;      // 65536
constexpr int NSTRIP = 256;           // n-rows per block (8 waves * 32)
constexpr int MHALF  = 4096;          // m-range per block
constexpr int CHUNK  = 512;           // m staged in LDS per chunk

__global__ __launch_bounds__(256) void pack_kernel(
    const float* __restrict__ in1, const float* __restrict__ in2,
    _Float16* __restrict__ Ap, _Float16* __restrict__ Bp,
    float* __restrict__ out)
{
    int i = blockIdx.x * 256 + threadIdx.x;
    if (i == 0) *out = 0.0f;          // zero the atomicAdd accumulator
    {
        float x = in1[3*i], y = in1[3*i+1], z = in1[3*i+2];
        float sq = fmaf(x, x, fmaf(y, y, z * z));
        _Float16 xh = (_Float16)x, yh = (_Float16)y, zh = (_Float16)z;
        _Float16 xl = (_Float16)(x - (float)xh);
        _Float16 yl = (_Float16)(y - (float)yh);
        _Float16 zl = (_Float16)(z - (float)zh);
        _Float16 sh = (_Float16)sq, sl = (_Float16)(sq - (float)sh);
        half8 lo = {xh, yh, zh, xl, yl, zl, xh, yh};
        half8 hi = {zh, sh, sl, (_Float16)1.f, (_Float16)1.f,
                    (_Float16)0.f, (_Float16)0.f, (_Float16)0.f};
        *(half8*)&Ap[16 * i] = lo;
        *(half8*)&Ap[16 * i + 8] = hi;
    }
    {
        float cx = in2[3*i], cy = in2[3*i+1], cz = in2[3*i+2];
        float x = -2.f * cx, y = -2.f * cy, z = -2.f * cz;
        float sq = fmaf(cx, cx, fmaf(cy, cy, cz * cz));
        _Float16 xh = (_Float16)x, yh = (_Float16)y, zh = (_Float16)z;
        _Float16 xl = (_Float16)(x - (float)xh);
        _Float16 yl = (_Float16)(y - (float)yh);
        _Float16 zl = (_Float16)(z - (float)zh);
        _Float16 sh = (_Float16)sq, sl = (_Float16)(sq - (float)sh);
        half8 lo = {xh, yh, zh, xh, yh, zh, xl, yl};
        half8 hi = {zl, (_Float16)1.f, (_Float16)1.f, sh, sl,
                    (_Float16)0.f, (_Float16)0.f, (_Float16)0.f};
        *(half8*)&Bp[16 * i] = lo;
        *(half8*)&Bp[16 * i + 8] = hi;
    }
}

// min3 tree over the 16 C-regs of one tile (column-min within a lane).
__device__ __forceinline__ float colmin16(const f16x& a)
{
    float m0 = fminf(fminf(a[0],  a[1]),  a[2]);    // v_min3
    float m1 = fminf(fminf(a[3],  a[4]),  a[5]);
    float m2 = fminf(fminf(a[6],  a[7]),  a[8]);
    float m3 = fminf(fminf(a[9],  a[10]), a[11]);
    float m4 = fminf(fminf(a[12], a[13]), a[14]);
    return fminf(fminf(fminf(m0, m1), m2), fminf(fminf(m3, m4), a[15]));
}

// grid (32, 2, 8), block 512 (8 waves x 32 n-rows).
// dist1 (min over m) folded in regs -> d1p[b][mh][n]  (unclamped).
// dist2 (min over n) via LDS atomicMin -> d2p[b][strip][m] (clamped).
__global__ __launch_bounds__(512, 4) void chamfer_mfma(
    const _Float16* __restrict__ Ap, const _Float16* __restrict__ Bp,
    float* __restrict__ d1p, float* __restrict__ d2p)
{
    const int b     = blockIdx.z;
    const int strip = blockIdx.x;
    const int mh    = blockIdx.y;
    const int wave  = threadIdx.x >> 6;
    const int lane  = threadIdx.x & 63;
    const int col   = lane & 31;
    const int half  = lane >> 5;

    __shared__ _Float16 ldsB[CHUNK * 16];      // 16 KiB
    __shared__ unsigned d2lds[MHALF];          // 16 KiB

    for (int i = threadIdx.x; i < MHALF; i += 512)
        d2lds[i] = 0xFFFFFFFFu;

    const int nbase = strip * NSTRIP + wave * 32;
    half8 afrag = *(const half8*)&Ap[((size_t)b * NPTS + nbase + col) * 16 + half * 8];

    f16x MN1, zero;
#pragma unroll
    for (int r = 0; r < 16; ++r) { MN1[r] = 1e30f; zero[r] = 0.0f; }

    const _Float16* BpB = Bp + ((size_t)b * NPTS + mh * MHALF) * 16;

    for (int c = 0; c < MHALF / CHUNK; ++c) {
        __syncthreads();
        const float4* src = (const float4*)(BpB + (size_t)c * CHUNK * 16);
        float4* dst = (float4*)ldsB;
        dst[threadIdx.x]       = src[threadIdx.x];
        dst[threadIdx.x + 512] = src[threadIdx.x + 512];
        __syncthreads();

#pragma unroll 2
        for (int t = 0; t < CHUNK / 32; t += 2) {
            half8 bfA = *(const half8*)&ldsB[((t    ) * 32 + col) * 16 + half * 8];
            half8 bfB = *(const half8*)&ldsB[((t + 1) * 32 + col) * 16 + half * 8];
            f16x accA = __builtin_amdgcn_mfma_f32_32x32x16_f16(afrag, bfA, zero, 0, 0, 0);
            f16x accB = __builtin_amdgcn_mfma_f32_32x32x16_f16(afrag, bfB, zero, 0, 0, 0);

            // dist1: per-reg running min across m (v_min3 per reg).
#pragma unroll
            for (int r = 0; r < 16; ++r)
                MN1[r] = fminf(fminf(MN1[r], accA[r]), accB[r]);

            // dist2: column-min of each tile, clamp, LDS atomicMin.
            float vA = fmaxf(colmin16(accA), 0.0f);
            atomicMin(&d2lds[c * CHUNK + t * 32 + col], __float_as_uint(vA));
            float vB = fmaxf(colmin16(accB), 0.0f);
            atomicMin(&d2lds[c * CHUNK + (t + 1) * 32 + col], __float_as_uint(vB));
        }
    }
    __syncthreads();

    float* d2 = d2p + ((size_t)b * 32 + strip) * NPTS + mh * MHALF;
    for (int i = threadIdx.x; i < MHALF; i += 512)
        d2[i] = __uint_as_float(d2lds[i]);

    // dist1: butterfly min across the 32 cols of each half, lane 0 of each
    // half writes its 16 rows: row = (r&3) + 8*(r>>2) + 4*half.
#pragma unroll
    for (int m = 1; m <= 16; m <<= 1)
#pragma unroll
        for (int r = 0; r < 16; ++r)
            MN1[r] = fminf(MN1[r], __shfl_xor(MN1[r], m, 64));
    if (col == 0) {
        float* d1 = d1p + ((size_t)b * 2 + mh) * NPTS + nbase;
#pragma unroll
        for (int r = 0; r < 16; ++r)
            d1[(r & 3) + 8 * (r >> 2) + 4 * half] = MN1[r];
    }
}

// One thread per 4 m's: fold 32 d2 strip-planes + 2 d1 planes (float4),
// sum, wave-reduce, atomicAdd(out, sum/TOTAL).
__global__ __launch_bounds__(256) void reduce_kernel(
    const float* __restrict__ d1p, const float* __restrict__ d2p,
    float* __restrict__ out)
{
    int g  = blockIdx.x * 256 + threadIdx.x;      // [0, TOTAL/4)
    int b  = g >> 11;
    int mq = g & 2047;                            // float4 index within batch

    const float4* p2 = (const float4*)(d2p + (size_t)b * 32 * NPTS) + mq;
    float4 v2 = p2[0];
#pragma unroll
    for (int s = 1; s < 32; ++s) {
        float4 t = p2[(size_t)s * (NPTS / 4)];
        v2.x = fminf(v2.x, t.x); v2.y = fminf(v2.y, t.y);
        v2.z = fminf(v2.z, t.z); v2.w = fminf(v2.w, t.w);
    }
    float4 a0 = ((const float4*)(d1p + ((size_t)b * 2 + 0) * NPTS))[mq];
    float4 a1 = ((const float4*)(d1p + ((size_t)b * 2 + 1) * NPTS))[mq];
    float v = fmaxf(fminf(a0.x, a1.x), 0.0f) + fmaxf(fminf(a0.y, a1.y), 0.0f)
            + fmaxf(fminf(a0.z, a1.z), 0.0f) + fmaxf(fminf(a0.w, a1.w), 0.0f)
            + v2.x + v2.y + v2.z + v2.w;

#pragma unroll
    for (int off = 32; off; off >>= 1)
        v += __shfl_down(v, off, 64);
    __shared__ float wsum[4];
    int lane = threadIdx.x & 63, w = threadIdx.x >> 6;
    if (lane == 0) wsum[w] = v;
    __syncthreads();
    if (threadIdx.x == 0)
        atomicAdd(out, (wsum[0] + wsum[1] + wsum[2] + wsum[3]) *
                           (1.0f / (float)TOTAL));
}

extern "C" void kernel_launch(void* const* d_in, const int* in_sizes, int n_in,
                              void* d_out, int out_size, void* d_ws, size_t ws_size,
                              hipStream_t stream)
{
    const float* in1 = (const float*)d_in[0];
    const float* in2 = (const float*)d_in[1];
    float* out = (float*)d_out;

    char* ws = (char*)d_ws;
    _Float16* Ap  = (_Float16*)ws;                            // 2 MiB
    _Float16* Bp  = (_Float16*)(ws + (size_t)TOTAL * 32);     // 2 MiB
    float*    d1p = (float*)(ws + (size_t)2 * TOTAL * 32);    // 512 KiB
    float*    d2p = (float*)(ws + (size_t)2 * TOTAL * 32 + (size_t)2 * TOTAL * 4); // 8 MiB

    pack_kernel<<<TOTAL / 256, 256, 0, stream>>>(in1, in2, Ap, Bp, out);
    chamfer_mfma<<<dim3(NPTS / NSTRIP, 2, B), 512, 0, stream>>>(Ap, Bp, d1p, d2p);
    reduce_kernel<<<TOTAL / 1024, 256, 0, stream>>>(d1p, d2p, out);
}

// Round 7
// 92.127 us; speedup vs baseline: 1.5942x; 1.0406x over previous
//
#include <hip/hip_runtime.h>

// Chamfer distance, B=8, N=M=8192, D=3, fp32 — fused MFMA formulation.
// Each fp32 split into f16 hi+lo (x = xh+xl, err ~2^-22). K=16 vectors:
//   A(n): [ah0,ah1,ah2, al0,al1,al2, ah0,ah1,ah2, sqh_n,sql_n, 1,1, 0,0,0]
//   B(m): [bh0,bh1,bh2, bh0,bh1,bh2, bl0,bl1,bl2, 1,1, sqh_m,sql_m, 0,0,0]
// with b = -2c (exact scale). One v_mfma_f32_32x32x16_f16 yields a 32x32
// tile of d(n,m) = sq_n + sq_m - 2<a,c> (+O(1e-5)). Each tile feeds BOTH
// mins: over m (dist1, reg fold) and over n (dist2, LDS atomicMin).
// Packing is fused: A-frags built in-register, B packed into LDS at stage.
// C/D: col=lane&31, row=(reg&3)+8*(reg>>2)+4*(lane>>5)  [HW-verified]
// A/B: row/col=lane&31, k=(lane>>5)*8+j                 [verified R5: absmax 0]

typedef _Float16 half8 __attribute__((ext_vector_type(8)));
typedef float    f16x  __attribute__((ext_vector_type(16)));

constexpr int B      = 8;
constexpr int NPTS   = 8192;
constexpr int TOTAL  = B * NPTS;      // 65536
constexpr int NSTRIP = 256;           // n-rows per block (8 waves * 32)
constexpr int MHALF  = 4096;          // m-range per block
constexpr int CHUNK  = 512;           // m staged in LDS per chunk

// min3 tree: min of 16 C-regs (column-min within a lane), 8 issues.
__device__ __forceinline__ float colmin16(const f16x& a)
{
    float m0 = fminf(fminf(a[0],  a[1]),  a[2]);
    float m1 = fminf(fminf(a[3],  a[4]),  a[5]);
    float m2 = fminf(fminf(a[6],  a[7]),  a[8]);
    float m3 = fminf(fminf(a[9],  a[10]), a[11]);
    float m4 = fminf(fminf(a[12], a[13]), a[14]);
    return fminf(fminf(fminf(m0, m1), m2), fminf(fminf(m3, m4), a[15]));
}

// grid (32, 2, 8), block 512 (8 waves x 32 n-rows).
// dist1 (min over m) folded in regs -> d1p[b][mh][n]  (unclamped).
// dist2 (min over n) via LDS atomicMin -> d2p[b][strip][m] (clamped).
__global__ __launch_bounds__(512, 4) void chamfer_mfma(
    const float* __restrict__ in1, const float* __restrict__ in2,
    float* __restrict__ d1p, float* __restrict__ d2p, float* __restrict__ out)
{
    const int b     = blockIdx.z;
    const int strip = blockIdx.x;
    const int mh    = blockIdx.y;
    const int wave  = threadIdx.x >> 6;
    const int lane  = threadIdx.x & 63;
    const int col   = lane & 31;
    const int half  = lane >> 5;

    if ((blockIdx.x | blockIdx.y | blockIdx.z) == 0 && threadIdx.x == 0)
        *out = 0.0f;                   // zero accumulator before reduce runs

    __shared__ _Float16 ldsB[CHUNK * 16];      // 16 KiB
    __shared__ unsigned d2lds[MHALF];          // 16 KiB

    for (int i = threadIdx.x; i < MHALF; i += 512)
        d2lds[i] = 0xFFFFFFFFu;

    // A fragment, packed in-register from raw in1.
    const int nbase = strip * NSTRIP + wave * 32;
    half8 afrag;
    {
        const float* a = in1 + ((size_t)b * NPTS + nbase + col) * 3;
        float x = a[0], y = a[1], z = a[2];
        float sq = fmaf(x, x, fmaf(y, y, z * z));
        _Float16 xh = (_Float16)x, yh = (_Float16)y, zh = (_Float16)z;
        _Float16 xl = (_Float16)(x - (float)xh);
        _Float16 yl = (_Float16)(y - (float)yh);
        _Float16 zl = (_Float16)(z - (float)zh);
        _Float16 sh = (_Float16)sq, sl = (_Float16)(sq - (float)sh);
        half8 lo = {xh, yh, zh, xl, yl, zl, xh, yh};
        half8 hi = {zh, sh, sl, (_Float16)1.f, (_Float16)1.f,
                    (_Float16)0.f, (_Float16)0.f, (_Float16)0.f};
        afrag = half ? hi : lo;
    }

    f16x MN1, zero;
#pragma unroll
    for (int r = 0; r < 16; ++r) { MN1[r] = 1e30f; zero[r] = 0.0f; }

    const float* Craw = in2 + ((size_t)b * NPTS + mh * MHALF) * 3;

    for (int c = 0; c < MHALF / CHUNK; ++c) {
        __syncthreads();
        // Stage + pack one candidate per thread into LDS (B layout).
        {
            const float* cp = Craw + (size_t)(c * CHUNK + threadIdx.x) * 3;
            float cx = cp[0], cy = cp[1], cz = cp[2];
            float x = -2.f * cx, y = -2.f * cy, z = -2.f * cz;
            float sq = fmaf(cx, cx, fmaf(cy, cy, cz * cz));
            _Float16 xh = (_Float16)x, yh = (_Float16)y, zh = (_Float16)z;
            _Float16 xl = (_Float16)(x - (float)xh);
            _Float16 yl = (_Float16)(y - (float)yh);
            _Float16 zl = (_Float16)(z - (float)zh);
            _Float16 sh = (_Float16)sq, sl = (_Float16)(sq - (float)sh);
            half8 lo = {xh, yh, zh, xh, yh, zh, xl, yl};
            half8 hi = {zl, (_Float16)1.f, (_Float16)1.f, sh, sl,
                        (_Float16)0.f, (_Float16)0.f, (_Float16)0.f};
            *(half8*)&ldsB[threadIdx.x * 16]     = lo;
            *(half8*)&ldsB[threadIdx.x * 16 + 8] = hi;
        }
        __syncthreads();

#pragma unroll 2
        for (int t = 0; t < CHUNK / 32; t += 2) {
            half8 bfA = *(const half8*)&ldsB[((t    ) * 32 + col) * 16 + half * 8];
            half8 bfB = *(const half8*)&ldsB[((t + 1) * 32 + col) * 16 + half * 8];
            f16x accA = __builtin_amdgcn_mfma_f32_32x32x16_f16(afrag, bfA, zero, 0, 0, 0);
            f16x accB = __builtin_amdgcn_mfma_f32_32x32x16_f16(afrag, bfB, zero, 0, 0, 0);

            // dist1: per-reg running min across m (v_min3 per reg).
#pragma unroll
            for (int r = 0; r < 16; ++r)
                MN1[r] = fminf(fminf(MN1[r], accA[r]), accB[r]);

            // dist2: column-min of each tile, clamp, LDS atomicMin.
            float vA = fmaxf(colmin16(accA), 0.0f);
            atomicMin(&d2lds[c * CHUNK + t * 32 + col], __float_as_uint(vA));
            float vB = fmaxf(colmin16(accB), 0.0f);
            atomicMin(&d2lds[c * CHUNK + (t + 1) * 32 + col], __float_as_uint(vB));
        }
    }
    __syncthreads();

    float* d2 = d2p + ((size_t)b * 32 + strip) * NPTS + mh * MHALF;
    for (int i = threadIdx.x; i < MHALF; i += 512)
        d2[i] = __uint_as_float(d2lds[i]);

    // dist1: butterfly min across the 32 cols of each half, lane 0 of each
    // half writes its 16 rows: row = (r&3) + 8*(r>>2) + 4*half.
#pragma unroll
    for (int m = 1; m <= 16; m <<= 1)
#pragma unroll
        for (int r = 0; r < 16; ++r)
            MN1[r] = fminf(MN1[r], __shfl_xor(MN1[r], m, 64));
    if (col == 0) {
        float* d1 = d1p + ((size_t)b * 2 + mh) * NPTS + nbase;
#pragma unroll
        for (int r = 0; r < 16; ++r)
            d1[(r & 3) + 8 * (r >> 2) + 4 * half] = MN1[r];
    }
}

// One thread per 4 m's: fold 32 d2 strip-planes + 2 d1 planes (float4),
// sum, wave-reduce, atomicAdd(out, sum/TOTAL).
__global__ __launch_bounds__(256) void reduce_kernel(
    const float* __restrict__ d1p, const float* __restrict__ d2p,
    float* __restrict__ out)
{
    int g  = blockIdx.x * 256 + threadIdx.x;      // [0, TOTAL/4)
    int b  = g >> 11;
    int mq = g & 2047;                            // float4 index within batch

    const float4* p2 = (const float4*)(d2p + (size_t)b * 32 * NPTS) + mq;
    float4 v2 = p2[0];
#pragma unroll
    for (int s = 1; s < 32; ++s) {
        float4 t = p2[(size_t)s * (NPTS / 4)];
        v2.x = fminf(v2.x, t.x); v2.y = fminf(v2.y, t.y);
        v2.z = fminf(v2.z, t.z); v2.w = fminf(v2.w, t.w);
    }
    float4 a0 = ((const float4*)(d1p + ((size_t)b * 2 + 0) * NPTS))[mq];
    float4 a1 = ((const float4*)(d1p + ((size_t)b * 2 + 1) * NPTS))[mq];
    float v = fmaxf(fminf(a0.x, a1.x), 0.0f) + fmaxf(fminf(a0.y, a1.y), 0.0f)
            + fmaxf(fminf(a0.z, a1.z), 0.0f) + fmaxf(fminf(a0.w, a1.w), 0.0f)
            + v2.x + v2.y + v2.z + v2.w;

#pragma unroll
    for (int off = 32; off; off >>= 1)
        v += __shfl_down(v, off, 64);
    __shared__ float wsum[4];
    int lane = threadIdx.x & 63, w = threadIdx.x >> 6;
    if (lane == 0) wsum[w] = v;
    __syncthreads();
    if (threadIdx.x == 0)
        atomicAdd(out, (wsum[0] + wsum[1] + wsum[2] + wsum[3]) *
                           (1.0f / (float)TOTAL));
}

extern "C" void kernel_launch(void* const* d_in, const int* in_sizes, int n_in,
                              void* d_out, int out_size, void* d_ws, size_t ws_size,
                              hipStream_t stream)
{
    const float* in1 = (const float*)d_in[0];
    const float* in2 = (const float*)d_in[1];
    float* out = (float*)d_out;

    char* ws = (char*)d_ws;
    float* d1p = (float*)ws;                              // 2*TOTAL*4 = 512 KiB
    float* d2p = (float*)(ws + (size_t)2 * TOTAL * 4);    // 32*TOTAL*4 = 8 MiB

    chamfer_mfma<<<dim3(NPTS / NSTRIP, 2, B), 512, 0, stream>>>(
        in1, in2, d1p, d2p, out);
    reduce_kernel<<<TOTAL / 1024, 256, 0, stream>>>(d1p, d2p, out);
}